// Round 28
// baseline (310.660 us; speedup 1.0000x reference)
//
#include <hip/hip_runtime.h>

// Path signature M=4, d=10, L=256, B=2048 — MFMA formulation, round 28.
// Algebra = r24/r27 (absmax 10.5): per t, S4 += a·(u+w/2) + r12·(-w/24);
// P=[a_hi,a_lo,r12], Q=[uw,uw,-w/24]; K=768, 10 t per K=32 chunk, 26 chunks;
// vcol rows = degenerate cells (i2 = zero row, Rv=1, exact).
// ROUND-28: LDS-BW attack. Per-chunk LDS traffic was 72.7 KB (chain reads 20.5
// + P/Q writes 16.4 + frag reads 35.8) -> ~15 MB/CU ≈ 49-70us of LDS pipe =
// the binder (explains r25/r26/r27 nulls). Transposed increments now staged to
// GLOBAL d_ws (11.6 KB/block slice, L1/L2-resident; concurrent set ~1.5MB/XCD)
// and chain reads issue on the idle VMEM pipe (5x global_load_dwordx2).
// -28% LDS traffic; vt LDS array deleted (LDS 40.4 -> 28.7 KB).
// Requires ws_size >= 2048*2904*4 B = 23.8 MB.

#define SIG  11110
#define NCH  26
#define WSTR 264                     // wt row stride (floats): 8B-aligned rows

typedef short bf16x8 __attribute__((ext_vector_type(8)));
typedef float f32x4  __attribute__((ext_vector_type(4)));

__device__ __forceinline__ unsigned cvt_pk2(float lo, float hi) {
    unsigned r;
    asm("v_cvt_pk_bf16_f32 %0, %1, %2" : "=v"(r) : "v"(lo), "v"(hi));
    return r;
}

template<int MI, int NI>
__device__ __forceinline__ void consume(const unsigned* __restrict__ Pb,
                                        const unsigned* __restrict__ Qb,
                                        int r0, int c0, int lane,
                                        f32x4 (&acc)[MI][NI]) {
    const int slot = lane >> 4, rr = lane & 15;
    bf16x8 Bf[NI];
    #pragma unroll
    for (int ni = 0; ni < NI; ++ni)
        Bf[ni] = *(const bf16x8*)(Qb + slot * 448 + (c0 + ni * 16 + rr) * 4);
    #pragma unroll
    for (int mi = 0; mi < MI; ++mi) {
        const bf16x8 Af = *(const bf16x8*)(Pb + slot * 448 + (r0 + mi * 16 + rr) * 4);
        #pragma unroll
        for (int ni = 0; ni < NI; ++ni)
            acc[mi][ni] = __builtin_amdgcn_mfma_f32_16x16x32_bf16(Af, Bf[ni], acc[mi][ni], 0, 0, 0);
    }
}

template<int MI, int NI>
__device__ __forceinline__ void write_seg(int r0, int c0, int lane,
                                          const f32x4 (&acc)[MI][NI],
                                          float* __restrict__ out, size_t base) {
    #pragma unroll
    for (int mi = 0; mi < MI; ++mi) {
        #pragma unroll
        for (int ni = 0; ni < NI; ++ni) {
            #pragma unroll
            for (int r = 0; r < 4; ++r) {
                const int m = r0 + mi * 16 + (lane >> 4) * 4 + r;
                const int n = c0 + ni * 16 + (lane & 15);
                if (m < 100) {
                    if (n < 100)      out[base + 1110 + m * 100 + n]         = acc[mi][ni][r];
                    else if (n < 110) out[base + 110  + m * 10  + (n - 100)] = acc[mi][ni][r];
                }
            }
        }
    }
}

__device__ __forceinline__ void produce(int ch, const float* __restrict__ wt,
                                        unsigned* __restrict__ Pb,
                                        unsigned* __restrict__ Qb,
                                        bool isPair, bool isQ,
                                        int prow, int qrow, int i1, int i2,
                                        float& s1f, float& Rv, float& Ds) {
    float v1[10], v2[10];
    {
        // chain reads from GLOBAL (L1/L2-hot) — VMEM pipe, not LDS
        const float* p1 = wt + i1 * WSTR + ch * 10;
        const float* p2 = wt + i2 * WSTR + ch * 10;
        #pragma unroll
        for (int k = 0; k < 5; ++k) {
            const float2 x = *(const float2*)(p1 + 2 * k);
            const float2 y = *(const float2*)(p2 + 2 * k);
            v1[2 * k] = x.x; v1[2 * k + 1] = x.y;
            v2[2 * k] = y.x; v2[2 * k + 1] = y.y;
        }
    }
    if (isPair) {
        float ah[10], al[10], rr[10];
        #pragma unroll
        for (int tl = 0; tl < 10; ++tl) {
            const float vi = v1[tl], vj = v2[tl];
            const float r1 = vi * vj;
            const float r2 = s1f * vj;
            const float a  = fmaf(r1, 1.f/6.f, fmaf(r2, 0.5f, Ds));
            const float hi = __uint_as_float(__float_as_uint(a) & 0xFFFF0000u);
            ah[tl] = hi; al[tl] = a - hi;          // exact residual
            rr[tl] = fmaf(2.f, r2, r1);            // r12 = r1 + 2·r2
            Ds += fmaf(0.5f, r1, r2);
            s1f += vi;
        }
        unsigned wd[15];
        #pragma unroll
        for (int m = 0; m < 5; ++m) {
            wd[3 * m + 0] = cvt_pk2(ah[2 * m],     al[2 * m]);
            wd[3 * m + 1] = cvt_pk2(rr[2 * m],     ah[2 * m + 1]);
            wd[3 * m + 2] = cvt_pk2(al[2 * m + 1], rr[2 * m + 1]);
        }
        *(uint4*)&Pb[0 * 448 + prow * 4] = make_uint4(wd[0],  wd[1],  wd[2],  wd[3]);
        *(uint4*)&Pb[1 * 448 + prow * 4] = make_uint4(wd[4],  wd[5],  wd[6],  wd[7]);
        *(uint4*)&Pb[2 * 448 + prow * 4] = make_uint4(wd[8],  wd[9],  wd[10], wd[11]);
        *(uint4*)&Pb[3 * 448 + prow * 4] = make_uint4(wd[12], wd[13], wd[14], 0u);
    } else if (isQ) {       // cells 0..99 AND vcols 100..109 (i2=zero row, Rv=1)
        float uw[10], mw[10];
        #pragma unroll
        for (int tl = 0; tl < 10; ++tl) {
            const float vk = v1[tl], vl = v2[tl];
            const float w  = vk * vl;
            const float m2 = fmaf(-0.5f, vl, Rv);  // cells: xL-(x_t+x_{t+1})/2; vcol: 1
            Rv -= vl;
            uw[tl] = vk * m2;                      // cells: u+w/2 ; vcol: v (exact)
            mw[tl] = w * (-1.f/24.f);
        }
        unsigned wd[15];
        #pragma unroll
        for (int m = 0; m < 5; ++m) {
            wd[3 * m + 0] = cvt_pk2(uw[2 * m],     uw[2 * m]);
            wd[3 * m + 1] = cvt_pk2(mw[2 * m],     uw[2 * m + 1]);
            wd[3 * m + 2] = cvt_pk2(uw[2 * m + 1], mw[2 * m + 1]);
        }
        *(uint4*)&Qb[0 * 448 + qrow * 4] = make_uint4(wd[0],  wd[1],  wd[2],  wd[3]);
        *(uint4*)&Qb[1 * 448 + qrow * 4] = make_uint4(wd[4],  wd[5],  wd[6],  wd[7]);
        *(uint4*)&Qb[2 * 448 + qrow * 4] = make_uint4(wd[8],  wd[9],  wd[10], wd[11]);
        *(uint4*)&Qb[3 * 448 + qrow * 4] = make_uint4(wd[12], wd[13], wd[14], 0u);
    }
}

// Whole chunk-loop per wave: exactly-sized accumulators. B segment optional (MIB=0).
template<int MIA, int NIA, int R0A, int C0A, int MIB, int NIB, int R0B, int C0B>
__device__ __forceinline__ void run_wave(const float* __restrict__ wt,
                                         unsigned (&Pl)[2][1792],
                                         unsigned (&Ql)[2][1792],
                                         bool isPair, bool isQ,
                                         int prow, int qrow, int i1, int i2,
                                         float s1f, float Rv,
                                         int lane, float* __restrict__ out, size_t base) {
    float Ds = 0.f;
    f32x4 accA[MIA][NIA];
    #pragma unroll
    for (int mi = 0; mi < MIA; ++mi)
        #pragma unroll
        for (int ni = 0; ni < NIA; ++ni) accA[mi][ni] = (f32x4){0.f, 0.f, 0.f, 0.f};
    constexpr int MB = (MIB > 0) ? MIB : 1;
    constexpr int NB = (NIB > 0) ? NIB : 1;
    f32x4 accB[MB][NB];
    if constexpr (MIB > 0) {
        #pragma unroll
        for (int mi = 0; mi < MB; ++mi)
            #pragma unroll
            for (int ni = 0; ni < NB; ++ni) accB[mi][ni] = (f32x4){0.f, 0.f, 0.f, 0.f};
    }

    produce(0, wt, Pl[0], Ql[0], isPair, isQ, prow, qrow, i1, i2, s1f, Rv, Ds);
    __syncthreads();

    for (int ch = 0; ch < NCH; ++ch) {
        const unsigned* Pb = Pl[ch & 1];
        const unsigned* Qb = Ql[ch & 1];
        consume<MIA, NIA>(Pb, Qb, R0A, C0A, lane, accA);
        if constexpr (MIB > 0) consume<MIB, NIB>(Pb, Qb, R0B, C0B, lane, accB);
        if (ch < NCH - 1)
            produce(ch + 1, wt, Pl[(ch + 1) & 1], Ql[(ch + 1) & 1],
                    isPair, isQ, prow, qrow, i1, i2, s1f, Rv, Ds);
        __syncthreads();   // 27 barriers in every instantiation — counts match
    }

    if (isPair) out[base + 10 + prow] = Ds;          // S2 exact
    write_seg<MIA, NIA>(R0A, C0A, lane, accA, out, base);
    if constexpr (MIB > 0) write_seg<MIB, NIB>(R0B, C0B, lane, accB, out, base);
}

__global__ __launch_bounds__(256, 4)
void sig_mfma21(const float* __restrict__ xg, float* __restrict__ out,
                float* __restrict__ wt_all) {
    __shared__ unsigned Pl[2][1792];       // dbuf [slot][112 rows][4w] 14336 B
    __shared__ unsigned Ql[2][1792];       //                           14336 B

    const int tid  = threadIdx.x;
    const int b    = blockIdx.x;
    const int lane = tid & 63;
    const int wv   = tid >> 6;
    const float* __restrict__ xb = xg + (size_t)b * 2560;
    float* wt = wt_all + (size_t)b * (11 * WSTR);

    // stage transposed increments [dim][264] to GLOBAL d_ws (coalesced writes;
    // slice is 11.6 KB -> L1/L2-hot for all later chain reads). Row 10 and
    // t >= 255 are zeros (tail + degenerate-vcol row).
    for (int o = tid; o < 11 * WSTR; o += 256) {
        const int d = o / WSTR, t = o - d * WSTR;
        float val = 0.f;
        if (d < 10 && t < 255) val = xb[(t + 1) * 10 + d] - xb[t * 10 + d];
        wt[o] = val;
    }
    // zero pads: P rows 100..111, Q rows 110..111 (both bufs)
    for (int e = tid; e < 384; e += 256) {
        const int buf = e / 192, r = e % 192, slot = r / 48, rem = r % 48;
        Pl[buf][slot * 448 + (100 + rem / 4) * 4 + (rem & 3)] = 0u;
    }
    if (tid < 64) {
        const int buf = tid / 32, r = tid % 32, slot = r / 8, rem = r % 8;
        Ql[buf][slot * 448 + (110 + rem / 4) * 4 + (rem & 3)] = 0u;
    }
    __threadfence();   // drain wt writes to L2
    __syncthreads();   // vmcnt(0)+barrier: wt + pads visible to all lanes

    // roles: waves 0-1 = Q rows (cells 0..99, vcols-as-cells 100..109);
    //        waves 2-3 = pair scan -> P
    const int  pid    = tid - 128;
    const bool isPair = (pid >= 0) && (pid < 100);
    const bool isQ    = (tid < 110);
    const int  prow   = isPair ? pid : 0;
    const int  qrow   = tid;

    int i1 = 0, i2 = 0;
    if (isPair)          { i1 = pid / 10; i2 = pid - i1 * 10; }
    else if (tid < 100)  { i1 = tid / 10; i2 = tid - i1 * 10; }   // cell
    else if (tid < 110)  { i1 = tid - 100; i2 = 10; }             // vcol: zero row

    const float s1f = 0.f;
    float Rv = 0.f;
    if (tid < 100)      Rv = xb[2550 + i2] - xb[i2];   // cell: xL - x0
    else if (tid < 110) Rv = 1.f;                      // vcol: m2 == 1 forever
    const size_t base = (size_t)b * SIG;

    // tile partition 12/13/12/12 (max 52 acc regs); Q waves take the 13:
    if      (wv == 0) run_wave<4, 3,  0, 48, 0, 0,  0,  0>(wt, Pl, Ql, isPair, isQ,
                          prow, qrow, i1, i2, s1f, Rv, lane, out, base);
    else if (wv == 1) run_wave<3, 3, 64, 48, 4, 1,  0, 96>(wt, Pl, Ql, isPair, isQ,
                          prow, qrow, i1, i2, s1f, Rv, lane, out, base);
    else if (wv == 2) run_wave<4, 3,  0,  0, 0, 0,  0,  0>(wt, Pl, Ql, isPair, isQ,
                          prow, qrow, i1, i2, s1f, Rv, lane, out, base);
    else              run_wave<3, 3, 64,  0, 3, 1, 64, 96>(wt, Pl, Ql, isPair, isQ,
                          prow, qrow, i1, i2, s1f, Rv, lane, out, base);

    if (tid < 10) out[base + tid] = xb[2550 + tid] - xb[tid];   // S1 exact
}

extern "C" void kernel_launch(void* const* d_in, const int* in_sizes, int n_in,
                              void* d_out, int out_size, void* d_ws, size_t ws_size,
                              hipStream_t stream) {
    const float* x = (const float*)d_in[0];
    float* out = (float*)d_out;
    const int B = in_sizes[0] / 2560;   // 2048 batches, one block each
    // wt workspace: B * 11 * 264 floats = 23.8 MB (assumes ws_size covers it)
    sig_mfma21<<<B, 256, 0, stream>>>(x, out, (float*)d_ws);
}

// Round 29
// 77.580 us; speedup vs baseline: 4.0044x; 4.0044x over previous
//
#include <hip/hip_runtime.h>

// Path signature M=4, d=10, L=256, B=2048 — MFMA formulation, round 29.
// = ROUND 27 (best, 75.8us) with ONE change: tile partition -> clean 2x2
// quadrants 16/12/12/9 (min frag-read partition: sum(|rows|+|cols|) = 28 b128
// vs 35 for the balanced 12/13/12/12). LDS pipe is the est. binder (40-60us of
// 76); frag reads are its largest component. Q waves (light produce) take the
// heavy quadrants. Exactly-sized acc per wave (r21); max 64 acc + ~56 arch =
// 120 < cap 128 (r19 precedent: 124 fits, no spill).
// Algebra (absmax 10.5): per t, S4 += a·(u+w/2) + r12·(-w/24), r12=r1+2r2;
// P=[a_hi,a_lo,r12], Q=[uw,uw,-w/24]; K=768, 10 t per chunk, 26 chunks;
// vcol rows = degenerate cells (i2=zero vt row, Rv=1). vt stride 262 (r27:
// conflict-free). consume(ch) then produce(ch+1) (r25: reorder regresses).

#define SIG  11110
#define NCH  26
#define VSTR 262

typedef short bf16x8 __attribute__((ext_vector_type(8)));
typedef float f32x4  __attribute__((ext_vector_type(4)));

__device__ __forceinline__ unsigned cvt_pk2(float lo, float hi) {
    unsigned r;
    asm("v_cvt_pk_bf16_f32 %0, %1, %2" : "=v"(r) : "v"(lo), "v"(hi));
    return r;
}

template<int MI, int NI>
__device__ __forceinline__ void consume(const unsigned* __restrict__ Pb,
                                        const unsigned* __restrict__ Qb,
                                        int r0, int c0, int lane,
                                        f32x4 (&acc)[MI][NI]) {
    const int slot = lane >> 4, rr = lane & 15;
    bf16x8 Bf[NI];
    #pragma unroll
    for (int ni = 0; ni < NI; ++ni)
        Bf[ni] = *(const bf16x8*)(Qb + slot * 448 + (c0 + ni * 16 + rr) * 4);
    #pragma unroll
    for (int mi = 0; mi < MI; ++mi) {
        const bf16x8 Af = *(const bf16x8*)(Pb + slot * 448 + (r0 + mi * 16 + rr) * 4);
        #pragma unroll
        for (int ni = 0; ni < NI; ++ni)
            acc[mi][ni] = __builtin_amdgcn_mfma_f32_16x16x32_bf16(Af, Bf[ni], acc[mi][ni], 0, 0, 0);
    }
}

template<int MI, int NI>
__device__ __forceinline__ void write_seg(int r0, int c0, int lane,
                                          const f32x4 (&acc)[MI][NI],
                                          float* __restrict__ out, size_t base) {
    #pragma unroll
    for (int mi = 0; mi < MI; ++mi) {
        #pragma unroll
        for (int ni = 0; ni < NI; ++ni) {
            #pragma unroll
            for (int r = 0; r < 4; ++r) {
                const int m = r0 + mi * 16 + (lane >> 4) * 4 + r;
                const int n = c0 + ni * 16 + (lane & 15);
                if (m < 100) {
                    if (n < 100)      out[base + 1110 + m * 100 + n]         = acc[mi][ni][r];
                    else if (n < 110) out[base + 110  + m * 10  + (n - 100)] = acc[mi][ni][r];
                }
            }
        }
    }
}

__device__ __forceinline__ void produce(int ch, const float* __restrict__ vt,
                                        unsigned* __restrict__ Pb,
                                        unsigned* __restrict__ Qb,
                                        bool isPair, bool isQ,
                                        int prow, int qrow, int i1, int i2,
                                        float& s1f, float& Rv, float& Ds) {
    float v1[10], v2[10];
    {
        const float* p1 = vt + i1 * VSTR + ch * 10;
        const float* p2 = vt + i2 * VSTR + ch * 10;
        #pragma unroll
        for (int k = 0; k < 5; ++k) {
            const float2 x = *(const float2*)(p1 + 2 * k);
            const float2 y = *(const float2*)(p2 + 2 * k);
            v1[2 * k] = x.x; v1[2 * k + 1] = x.y;
            v2[2 * k] = y.x; v2[2 * k + 1] = y.y;
        }
    }
    if (isPair) {
        float ah[10], al[10], rr[10];
        #pragma unroll
        for (int tl = 0; tl < 10; ++tl) {
            const float vi = v1[tl], vj = v2[tl];
            const float r1 = vi * vj;
            const float r2 = s1f * vj;
            const float a  = fmaf(r1, 1.f/6.f, fmaf(r2, 0.5f, Ds));
            const float hi = __uint_as_float(__float_as_uint(a) & 0xFFFF0000u);
            ah[tl] = hi; al[tl] = a - hi;          // exact residual
            rr[tl] = fmaf(2.f, r2, r1);            // r12 = r1 + 2·r2
            Ds += fmaf(0.5f, r1, r2);
            s1f += vi;
        }
        unsigned wd[15];
        #pragma unroll
        for (int m = 0; m < 5; ++m) {
            wd[3 * m + 0] = cvt_pk2(ah[2 * m],     al[2 * m]);
            wd[3 * m + 1] = cvt_pk2(rr[2 * m],     ah[2 * m + 1]);
            wd[3 * m + 2] = cvt_pk2(al[2 * m + 1], rr[2 * m + 1]);
        }
        *(uint4*)&Pb[0 * 448 + prow * 4] = make_uint4(wd[0],  wd[1],  wd[2],  wd[3]);
        *(uint4*)&Pb[1 * 448 + prow * 4] = make_uint4(wd[4],  wd[5],  wd[6],  wd[7]);
        *(uint4*)&Pb[2 * 448 + prow * 4] = make_uint4(wd[8],  wd[9],  wd[10], wd[11]);
        *(uint4*)&Pb[3 * 448 + prow * 4] = make_uint4(wd[12], wd[13], wd[14], 0u);
    } else if (isQ) {       // cells 0..99 AND vcols 100..109 (i2=zero row, Rv=1)
        float uw[10], mw[10];
        #pragma unroll
        for (int tl = 0; tl < 10; ++tl) {
            const float vk = v1[tl], vl = v2[tl];
            const float w  = vk * vl;
            const float m2 = fmaf(-0.5f, vl, Rv);  // cells: xL-(x_t+x_{t+1})/2; vcol: 1
            Rv -= vl;
            uw[tl] = vk * m2;                      // cells: u+w/2 ; vcol: v (exact)
            mw[tl] = w * (-1.f/24.f);
        }
        unsigned wd[15];
        #pragma unroll
        for (int m = 0; m < 5; ++m) {
            wd[3 * m + 0] = cvt_pk2(uw[2 * m],     uw[2 * m]);
            wd[3 * m + 1] = cvt_pk2(mw[2 * m],     uw[2 * m + 1]);
            wd[3 * m + 2] = cvt_pk2(uw[2 * m + 1], mw[2 * m + 1]);
        }
        *(uint4*)&Qb[0 * 448 + qrow * 4] = make_uint4(wd[0],  wd[1],  wd[2],  wd[3]);
        *(uint4*)&Qb[1 * 448 + qrow * 4] = make_uint4(wd[4],  wd[5],  wd[6],  wd[7]);
        *(uint4*)&Qb[2 * 448 + qrow * 4] = make_uint4(wd[8],  wd[9],  wd[10], wd[11]);
        *(uint4*)&Qb[3 * 448 + qrow * 4] = make_uint4(wd[12], wd[13], wd[14], 0u);
    }
}

// Whole chunk-loop per wave: single exactly-sized accumulator rectangle.
template<int MI, int NI, int R0, int C0>
__device__ __forceinline__ void run_wave(const float* __restrict__ vt,
                                         unsigned (&Pl)[2][1792],
                                         unsigned (&Ql)[2][1792],
                                         bool isPair, bool isQ,
                                         int prow, int qrow, int i1, int i2,
                                         float s1f, float Rv,
                                         int lane, float* __restrict__ out, size_t base) {
    float Ds = 0.f;
    f32x4 acc[MI][NI];
    #pragma unroll
    for (int mi = 0; mi < MI; ++mi)
        #pragma unroll
        for (int ni = 0; ni < NI; ++ni) acc[mi][ni] = (f32x4){0.f, 0.f, 0.f, 0.f};

    produce(0, vt, Pl[0], Ql[0], isPair, isQ, prow, qrow, i1, i2, s1f, Rv, Ds);
    __syncthreads();

    for (int ch = 0; ch < NCH; ++ch) {
        const unsigned* Pb = Pl[ch & 1];
        const unsigned* Qb = Ql[ch & 1];
        consume<MI, NI>(Pb, Qb, R0, C0, lane, acc);
        if (ch < NCH - 1)
            produce(ch + 1, vt, Pl[(ch + 1) & 1], Ql[(ch + 1) & 1],
                    isPair, isQ, prow, qrow, i1, i2, s1f, Rv, Ds);
        __syncthreads();   // 27 barriers in every instantiation — counts match
    }

    if (isPair) out[base + 10 + prow] = Ds;          // S2 exact
    write_seg<MI, NI>(R0, C0, lane, acc, out, base);
}

__global__ __launch_bounds__(256, 4)
void sig_mfma22(const float* __restrict__ xg, float* __restrict__ out) {
    __shared__ float    vt[11 * VSTR];     // increments [dim][262]; row 10 = zeros
    __shared__ unsigned Pl[2][1792];       // dbuf [slot][112 rows][4w] 14336 B
    __shared__ unsigned Ql[2][1792];       //                           14336 B

    const int tid  = threadIdx.x;
    const int b    = blockIdx.x;
    const int lane = tid & 63;
    const int wv   = tid >> 6;
    const float* __restrict__ xb = xg + (size_t)b * 2560;

    // stage increments transposed (coalesced global reads; L1 absorbs the x2)
    for (int e = tid; e < 2550; e += 256) {
        const int t = e / 10, d = e - t * 10;
        vt[d * VSTR + t] = xb[e + 10] - xb[e];
    }
    if (tid < 70) {                                       // t 255..261 = 0 (rows 0..9)
        const int d = tid / 7, k = tid % 7;
        vt[d * VSTR + 255 + k] = 0.f;
    }
    for (int e = tid; e < VSTR; e += 256) vt[10 * VSTR + e] = 0.f;  // zero dim row
    // zero pads: P rows 100..111, Q rows 110..111 (both bufs)
    for (int e = tid; e < 384; e += 256) {
        const int buf = e / 192, r = e % 192, slot = r / 48, rem = r % 48;
        Pl[buf][slot * 448 + (100 + rem / 4) * 4 + (rem & 3)] = 0u;
    }
    if (tid < 64) {
        const int buf = tid / 32, r = tid % 32, slot = r / 8, rem = r % 8;
        Ql[buf][slot * 448 + (110 + rem / 4) * 4 + (rem & 3)] = 0u;
    }
    __syncthreads();   // staging visible BEFORE produce(0) (r12/r13 lesson)

    // roles: waves 0-1 = Q rows (cells 0..99, vcols-as-cells 100..109);
    //        waves 2-3 = pair scan -> P
    const int  pid    = tid - 128;
    const bool isPair = (pid >= 0) && (pid < 100);
    const bool isQ    = (tid < 110);
    const int  prow   = isPair ? pid : 0;
    const int  qrow   = tid;

    int i1 = 0, i2 = 0;
    if (isPair)          { i1 = pid / 10; i2 = pid - i1 * 10; }
    else if (tid < 100)  { i1 = tid / 10; i2 = tid - i1 * 10; }   // cell
    else if (tid < 110)  { i1 = tid - 100; i2 = 10; }             // vcol: zero row

    const float s1f = 0.f;
    float Rv = 0.f;
    if (tid < 100)      Rv = xb[2550 + i2] - xb[i2];   // cell: xL - x0
    else if (tid < 110) Rv = 1.f;                      // vcol: m2 == 1 forever
    const size_t base = (size_t)b * SIG;

    // min-frag-read quadrant partition (frag cost 8/7/7/6 = 28 b128):
    //   w0 Q:    rows  0-63  x cols  0-63  (4x4=16, acc 64)
    //   w1 Q:    rows  0-63  x cols 64-111 (4x3=12, acc 48)
    //   w2 pair: rows 64-111 x cols  0-63  (3x4=12, acc 48)
    //   w3 pair: rows 64-111 x cols 64-111 (3x3= 9, acc 36)
    if      (wv == 0) run_wave<4, 4,  0,  0>(vt, Pl, Ql, isPair, isQ,
                          prow, qrow, i1, i2, s1f, Rv, lane, out, base);
    else if (wv == 1) run_wave<4, 3,  0, 64>(vt, Pl, Ql, isPair, isQ,
                          prow, qrow, i1, i2, s1f, Rv, lane, out, base);
    else if (wv == 2) run_wave<3, 4, 64,  0>(vt, Pl, Ql, isPair, isQ,
                          prow, qrow, i1, i2, s1f, Rv, lane, out, base);
    else              run_wave<3, 3, 64, 64>(vt, Pl, Ql, isPair, isQ,
                          prow, qrow, i1, i2, s1f, Rv, lane, out, base);

    if (tid < 10) out[base + tid] = xb[2550 + tid] - xb[tid];   // S1 exact
}

extern "C" void kernel_launch(void* const* d_in, const int* in_sizes, int n_in,
                              void* d_out, int out_size, void* d_ws, size_t ws_size,
                              hipStream_t stream) {
    const float* x = (const float*)d_in[0];
    float* out = (float*)d_out;
    const int B = in_sizes[0] / 2560;   // 2048 batches, one block each
    sig_mfma22<<<B, 256, 0, stream>>>(x, out);
}

// Round 30
// 75.790 us; speedup vs baseline: 4.0990x; 1.0236x over previous
//
#include <hip/hip_runtime.h>

// Path signature M=4, d=10, L=256, B=2048 — FINAL (= round 27 best, 75.8us).
// Algebra (absmax 10.5): unrolled Chen recurrence with closed-form prefix/suffix:
//   per t: S4 += a·(u+w/2) + r12·(-w/24), r12=r1+2r2, a=r1/6+r2/2+S2;
//   r1=vi·vj, r2=S1_i·vj, u=vk·R, w=vk·vl; S3 via vcol-as-degenerate-cell.
// GEMM C[112,112] = P^T Q, K=768: per-t K-rows P=[a_hi,a_lo,r12] (bf16 hi/lo
// split on the scan-side 'a' — load-bearing, r12 proved Q-side split fails),
// Q=[uw,uw,-w/24]; 10 t per K=32 chunk, 26 chunks, t>=255 zero-padded.
// Structure: one block/batch; waves 0-1 produce Q (cells + vcols-as-cells),
// waves 2-3 run the S2 scan -> P; every wave also consumes a templated,
// exactly-sized C-tile set (12/13/12/12, max 52 acc regs — the r21 occupancy
// unlock); double-buffered slot-major P/Q [slot][112][16B]; 1 barrier/chunk;
// vt transposed increments, stride 262 (conflict-free); launch_bounds(256,4).
// Measured-null/negative variants (do not revisit): produce-before-consume
// (r25), producer rebalance 15/14 (r26), global-ws chains (r28), min-frag
// quadrants w/ 64-acc (r29), K=64 chunks (r20), wave specialization (r18/19).

#define SIG  11110
#define NCH  26
#define VSTR 262

typedef short bf16x8 __attribute__((ext_vector_type(8)));
typedef float f32x4  __attribute__((ext_vector_type(4)));

__device__ __forceinline__ unsigned cvt_pk2(float lo, float hi) {
    unsigned r;
    asm("v_cvt_pk_bf16_f32 %0, %1, %2" : "=v"(r) : "v"(lo), "v"(hi));
    return r;
}

template<int MI, int NI>
__device__ __forceinline__ void consume(const unsigned* __restrict__ Pb,
                                        const unsigned* __restrict__ Qb,
                                        int r0, int c0, int lane,
                                        f32x4 (&acc)[MI][NI]) {
    const int slot = lane >> 4, rr = lane & 15;
    bf16x8 Bf[NI];
    #pragma unroll
    for (int ni = 0; ni < NI; ++ni)
        Bf[ni] = *(const bf16x8*)(Qb + slot * 448 + (c0 + ni * 16 + rr) * 4);
    #pragma unroll
    for (int mi = 0; mi < MI; ++mi) {
        const bf16x8 Af = *(const bf16x8*)(Pb + slot * 448 + (r0 + mi * 16 + rr) * 4);
        #pragma unroll
        for (int ni = 0; ni < NI; ++ni)
            acc[mi][ni] = __builtin_amdgcn_mfma_f32_16x16x32_bf16(Af, Bf[ni], acc[mi][ni], 0, 0, 0);
    }
}

template<int MI, int NI>
__device__ __forceinline__ void write_seg(int r0, int c0, int lane,
                                          const f32x4 (&acc)[MI][NI],
                                          float* __restrict__ out, size_t base) {
    #pragma unroll
    for (int mi = 0; mi < MI; ++mi) {
        #pragma unroll
        for (int ni = 0; ni < NI; ++ni) {
            #pragma unroll
            for (int r = 0; r < 4; ++r) {
                const int m = r0 + mi * 16 + (lane >> 4) * 4 + r;
                const int n = c0 + ni * 16 + (lane & 15);
                if (m < 100) {
                    if (n < 100)      out[base + 1110 + m * 100 + n]         = acc[mi][ni][r];
                    else if (n < 110) out[base + 110  + m * 10  + (n - 100)] = acc[mi][ni][r];
                }
            }
        }
    }
}

__device__ __forceinline__ void produce(int ch, const float* __restrict__ vt,
                                        unsigned* __restrict__ Pb,
                                        unsigned* __restrict__ Qb,
                                        bool isPair, bool isQ,
                                        int prow, int qrow, int i1, int i2,
                                        float& s1f, float& Rv, float& Ds) {
    float v1[10], v2[10];
    {
        const float* p1 = vt + i1 * VSTR + ch * 10;
        const float* p2 = vt + i2 * VSTR + ch * 10;
        #pragma unroll
        for (int k = 0; k < 5; ++k) {
            const float2 x = *(const float2*)(p1 + 2 * k);
            const float2 y = *(const float2*)(p2 + 2 * k);
            v1[2 * k] = x.x; v1[2 * k + 1] = x.y;
            v2[2 * k] = y.x; v2[2 * k + 1] = y.y;
        }
    }
    if (isPair) {
        float ah[10], al[10], rr[10];
        #pragma unroll
        for (int tl = 0; tl < 10; ++tl) {
            const float vi = v1[tl], vj = v2[tl];
            const float r1 = vi * vj;
            const float r2 = s1f * vj;
            const float a  = fmaf(r1, 1.f/6.f, fmaf(r2, 0.5f, Ds));
            const float hi = __uint_as_float(__float_as_uint(a) & 0xFFFF0000u);
            ah[tl] = hi; al[tl] = a - hi;          // exact residual
            rr[tl] = fmaf(2.f, r2, r1);            // r12 = r1 + 2·r2
            Ds += fmaf(0.5f, r1, r2);
            s1f += vi;
        }
        unsigned wd[15];
        #pragma unroll
        for (int m = 0; m < 5; ++m) {
            wd[3 * m + 0] = cvt_pk2(ah[2 * m],     al[2 * m]);
            wd[3 * m + 1] = cvt_pk2(rr[2 * m],     ah[2 * m + 1]);
            wd[3 * m + 2] = cvt_pk2(al[2 * m + 1], rr[2 * m + 1]);
        }
        *(uint4*)&Pb[0 * 448 + prow * 4] = make_uint4(wd[0],  wd[1],  wd[2],  wd[3]);
        *(uint4*)&Pb[1 * 448 + prow * 4] = make_uint4(wd[4],  wd[5],  wd[6],  wd[7]);
        *(uint4*)&Pb[2 * 448 + prow * 4] = make_uint4(wd[8],  wd[9],  wd[10], wd[11]);
        *(uint4*)&Pb[3 * 448 + prow * 4] = make_uint4(wd[12], wd[13], wd[14], 0u);
    } else if (isQ) {       // cells 0..99 AND vcols 100..109 (i2=zero row, Rv=1)
        float uw[10], mw[10];
        #pragma unroll
        for (int tl = 0; tl < 10; ++tl) {
            const float vk = v1[tl], vl = v2[tl];
            const float w  = vk * vl;
            const float m2 = fmaf(-0.5f, vl, Rv);  // cells: xL-(x_t+x_{t+1})/2; vcol: 1
            Rv -= vl;
            uw[tl] = vk * m2;                      // cells: u+w/2 ; vcol: v (exact)
            mw[tl] = w * (-1.f/24.f);
        }
        unsigned wd[15];
        #pragma unroll
        for (int m = 0; m < 5; ++m) {
            wd[3 * m + 0] = cvt_pk2(uw[2 * m],     uw[2 * m]);
            wd[3 * m + 1] = cvt_pk2(mw[2 * m],     uw[2 * m + 1]);
            wd[3 * m + 2] = cvt_pk2(uw[2 * m + 1], mw[2 * m + 1]);
        }
        *(uint4*)&Qb[0 * 448 + qrow * 4] = make_uint4(wd[0],  wd[1],  wd[2],  wd[3]);
        *(uint4*)&Qb[1 * 448 + qrow * 4] = make_uint4(wd[4],  wd[5],  wd[6],  wd[7]);
        *(uint4*)&Qb[2 * 448 + qrow * 4] = make_uint4(wd[8],  wd[9],  wd[10], wd[11]);
        *(uint4*)&Qb[3 * 448 + qrow * 4] = make_uint4(wd[12], wd[13], wd[14], 0u);
    }
}

// Whole chunk-loop per wave: exactly-sized accumulators. B segment optional (MIB=0).
template<int MIA, int NIA, int R0A, int C0A, int MIB, int NIB, int R0B, int C0B>
__device__ __forceinline__ void run_wave(const float* __restrict__ vt,
                                         unsigned (&Pl)[2][1792],
                                         unsigned (&Ql)[2][1792],
                                         bool isPair, bool isQ,
                                         int prow, int qrow, int i1, int i2,
                                         float s1f, float Rv,
                                         int lane, float* __restrict__ out, size_t base) {
    float Ds = 0.f;
    f32x4 accA[MIA][NIA];
    #pragma unroll
    for (int mi = 0; mi < MIA; ++mi)
        #pragma unroll
        for (int ni = 0; ni < NIA; ++ni) accA[mi][ni] = (f32x4){0.f, 0.f, 0.f, 0.f};
    constexpr int MB = (MIB > 0) ? MIB : 1;
    constexpr int NB = (NIB > 0) ? NIB : 1;
    f32x4 accB[MB][NB];
    if constexpr (MIB > 0) {
        #pragma unroll
        for (int mi = 0; mi < MB; ++mi)
            #pragma unroll
            for (int ni = 0; ni < NB; ++ni) accB[mi][ni] = (f32x4){0.f, 0.f, 0.f, 0.f};
    }

    produce(0, vt, Pl[0], Ql[0], isPair, isQ, prow, qrow, i1, i2, s1f, Rv, Ds);
    __syncthreads();

    for (int ch = 0; ch < NCH; ++ch) {
        const unsigned* Pb = Pl[ch & 1];
        const unsigned* Qb = Ql[ch & 1];
        consume<MIA, NIA>(Pb, Qb, R0A, C0A, lane, accA);
        if constexpr (MIB > 0) consume<MIB, NIB>(Pb, Qb, R0B, C0B, lane, accB);
        if (ch < NCH - 1)
            produce(ch + 1, vt, Pl[(ch + 1) & 1], Ql[(ch + 1) & 1],
                    isPair, isQ, prow, qrow, i1, i2, s1f, Rv, Ds);
        __syncthreads();   // 27 barriers in every instantiation — counts match
    }

    if (isPair) out[base + 10 + prow] = Ds;          // S2 exact
    write_seg<MIA, NIA>(R0A, C0A, lane, accA, out, base);
    if constexpr (MIB > 0) write_seg<MIB, NIB>(R0B, C0B, lane, accB, out, base);
}

__global__ __launch_bounds__(256, 4)
void sig_final(const float* __restrict__ xg, float* __restrict__ out) {
    __shared__ float    vt[11 * VSTR];     // increments [dim][262]; row 10 = zeros
    __shared__ unsigned Pl[2][1792];       // dbuf [slot][112 rows][4w] 14336 B
    __shared__ unsigned Ql[2][1792];       //                           14336 B

    const int tid  = threadIdx.x;
    const int b    = blockIdx.x;
    const int lane = tid & 63;
    const int wv   = tid >> 6;
    const float* __restrict__ xb = xg + (size_t)b * 2560;

    // stage increments transposed (coalesced global reads; L1 absorbs the x2)
    for (int e = tid; e < 2550; e += 256) {
        const int t = e / 10, d = e - t * 10;
        vt[d * VSTR + t] = xb[e + 10] - xb[e];
    }
    if (tid < 70) {                                       // t 255..261 = 0 (rows 0..9)
        const int d = tid / 7, k = tid % 7;
        vt[d * VSTR + 255 + k] = 0.f;
    }
    for (int e = tid; e < VSTR; e += 256) vt[10 * VSTR + e] = 0.f;  // zero dim row
    // zero pads: P rows 100..111, Q rows 110..111 (both bufs)
    for (int e = tid; e < 384; e += 256) {
        const int buf = e / 192, r = e % 192, slot = r / 48, rem = r % 48;
        Pl[buf][slot * 448 + (100 + rem / 4) * 4 + (rem & 3)] = 0u;
    }
    if (tid < 64) {
        const int buf = tid / 32, r = tid % 32, slot = r / 8, rem = r % 8;
        Ql[buf][slot * 448 + (110 + rem / 4) * 4 + (rem & 3)] = 0u;
    }
    __syncthreads();   // staging visible BEFORE produce(0)

    // roles: waves 0-1 = Q rows (cells 0..99, vcols-as-cells 100..109);
    //        waves 2-3 = pair scan -> P
    const int  pid    = tid - 128;
    const bool isPair = (pid >= 0) && (pid < 100);
    const bool isQ    = (tid < 110);
    const int  prow   = isPair ? pid : 0;
    const int  qrow   = tid;

    int i1 = 0, i2 = 0;
    if (isPair)          { i1 = pid / 10; i2 = pid - i1 * 10; }
    else if (tid < 100)  { i1 = tid / 10; i2 = tid - i1 * 10; }   // cell
    else if (tid < 110)  { i1 = tid - 100; i2 = 10; }             // vcol: zero row

    const float s1f = 0.f;
    float Rv = 0.f;
    if (tid < 100)      Rv = xb[2550 + i2] - xb[i2];   // cell: xL - x0
    else if (tid < 110) Rv = 1.f;                      // vcol: m2 == 1 forever
    const size_t base = (size_t)b * SIG;

    // tile partition 12/13/12/12 (max 52 acc regs); Q waves take the 13:
    if      (wv == 0) run_wave<4, 3,  0, 48, 0, 0,  0,  0>(vt, Pl, Ql, isPair, isQ,
                          prow, qrow, i1, i2, s1f, Rv, lane, out, base);
    else if (wv == 1) run_wave<3, 3, 64, 48, 4, 1,  0, 96>(vt, Pl, Ql, isPair, isQ,
                          prow, qrow, i1, i2, s1f, Rv, lane, out, base);
    else if (wv == 2) run_wave<4, 3,  0,  0, 0, 0,  0,  0>(vt, Pl, Ql, isPair, isQ,
                          prow, qrow, i1, i2, s1f, Rv, lane, out, base);
    else              run_wave<3, 3, 64,  0, 3, 1, 64, 96>(vt, Pl, Ql, isPair, isQ,
                          prow, qrow, i1, i2, s1f, Rv, lane, out, base);

    if (tid < 10) out[base + tid] = xb[2550 + tid] - xb[tid];   // S1 exact
}

extern "C" void kernel_launch(void* const* d_in, const int* in_sizes, int n_in,
                              void* d_out, int out_size, void* d_ws, size_t ws_size,
                              hipStream_t stream) {
    const float* x = (const float*)d_in[0];
    float* out = (float*)d_out;
    const int B = in_sizes[0] / 2560;   // 2048 batches, one block each
    sig_final<<<B, 256, 0, stream>>>(x, out);
}